// Round 3
// baseline (151.957 us; speedup 1.0000x reference)
//
#include <hip/hip_runtime.h>

typedef unsigned int   u32;
typedef unsigned short u16;
typedef short bf16x8 __attribute__((ext_vector_type(8)));
typedef float f32x4  __attribute__((ext_vector_type(4)));
typedef float f32x2  __attribute__((ext_vector_type(2)));

#define CIN   128
#define COUT  128
#define Hh    64
#define Ww    64
#define Bb    8
#define NKSTEP 36          // KDIM/32
#define XT_ELEMS (Bb*Hh*Ww*CIN)   // 4,194,304 ushorts (8 MB)

// ---- helpers ----------------------------------------------------------
__device__ __forceinline__ float bflo(u32 u){ return __uint_as_float(u << 16); }
__device__ __forceinline__ float bfhi(u32 u){ return __uint_as_float(u & 0xffff0000u); }

// fast f32x2 -> packed bf16 pair: round-half-up (+0x8000) then byte-perm.
// 3 VALU vs ~8 for RNE packbf; tie-bias negligible vs 0.039 threshold.
__device__ __forceinline__ u32 pack2(float a, float b){
    u32 lo = __float_as_uint(a) + 0x8000u;
    u32 hi = __float_as_uint(b) + 0x8000u;
    return __builtin_amdgcn_perm(hi, lo, 0x07060302u);
}
__device__ __forceinline__ u16 tobf(float a){
    u32 ua = __float_as_uint(a);
    ua += 0x7fffu + ((ua >> 16) & 1u);
    return (u16)(ua >> 16);
}

// ---- kernel 1: x [B,CIN,H,W] f32 -> xT [B,H,W,CIN] bf16 ---------------
// 128cin x 64hw tiles; coalesced 128B reads; LDS transpose (pad 132);
// full-128B-line NHWC writes.
__global__ __launch_bounds__(256) void k_transpose(const float* __restrict__ x,
                                                   u16* __restrict__ xT){
    __shared__ float lds[64*132];
    int bi = blockIdx.x;
    int hb = bi & 63, b = bi >> 6;
    int tid = threadIdx.x;

    {   // phase 1: read 128 cin-rows x 64 hw, write transposed to LDS
        int r = tid >> 1, cq = tid & 1;           // r: cin row, cq: hw half
        const float* xp = x + ((size_t)(b*128 + r))*4096 + hb*64 + cq*32;
        float4 v[8];
#pragma unroll
        for (int k = 0; k < 8; ++k) v[k] = *(const float4*)(xp + k*4);
        float* dst = lds + (cq*32)*132 + r;       // lds[hw][cin], stride 132
#pragma unroll
        for (int k = 0; k < 8; ++k){
            dst[(k*4+0)*132] = v[k].x;
            dst[(k*4+1)*132] = v[k].y;
            dst[(k*4+2)*132] = v[k].z;
            dst[(k*4+3)*132] = v[k].w;
        }
    }
    __syncthreads();
    {   // phase 2: per hw row, pack 32 cin -> 16 dwords, full-line stores
        int s = tid >> 2, kq = tid & 3;
        const float* src = lds + s*132 + kq*32;
        u32 r16[16];
#pragma unroll
        for (int k = 0; k < 8; ++k){
            float4 v = *(const float4*)(src + k*4);
            r16[k*2  ] = pack2(v.x, v.y);
            r16[k*2+1] = pack2(v.z, v.w);
        }
        u32* dst = (u32*)xT + ((size_t)(b*4096 + hb*64 + s))*64 + kq*16;
#pragma unroll
        for (int k = 0; k < 4; ++k)
            *(uint4*)(dst + k*4) = *(uint4*)&r16[k*4];
    }
}

// ---- kernel 2: weight [COUT,CIN,3,3] f32 -> Wt bf16, A-fragment order --
__global__ __launch_bounds__(256) void k_wprep(const float* __restrict__ w,
                                               u16* __restrict__ Wt){
    int gid = blockIdx.x*256 + threadIdx.x;     // 0 .. 147455
    int jf   = gid & 7;
    int lane = (gid >> 3) & 63;
    int mt   = (gid >> 9) & 7;
    int kt   = gid >> 12;
    int m  = mt*16 + (lane & 15);
    int kk = (lane >> 4)*8 + jf;
    int ck = kt*32 + kk;
    int kpos = ck >> 7;
    int cin  = ck & 127;
    Wt[gid] = tobf(w[((size_t)m*128 + cin)*9 + kpos]);
}

// ---- kernel 3: barrier-free fused deform-im2col + MFMA GEMM -----------
// grid 512: b = bi&7 (XCD-local batch), t = bi>>3 = ho row; tile 128cout x 64pos.
// Each thread self-produces its MFMA B-fragments (pos = wn*32 + jt*16 + l16,
// cin octet = quad): no LDS, no __syncthreads. Gathers pipelined depth-2,
// A-frags depth-1, offsets 4 iters ahead; state double-buffered by kpos parity.
__global__ __launch_bounds__(256, 2)
void k_main(const float* __restrict__ off, const float* __restrict__ bias,
            const u16* __restrict__ xT, const u16* __restrict__ Wt,
            float* __restrict__ out){
    int tid = threadIdx.x, bi = blockIdx.x;
    int b = bi & 7, t = bi >> 3, s0 = t * 64;
    int lane = tid & 63, wave = tid >> 6;
    int wm = wave >> 1, wn = wave & 1;
    int quad = lane >> 4, l16 = lane & 15;
    int p0 = wn*32 + l16, p1 = p0 + 16;       // this thread's two positions

    const u16* xb = xT + (size_t)b * (4096*128);
    const float* offb = off + (size_t)b * (18*4096) + s0;

    f32x4 acc[4][2];
#pragma unroll
    for (int i = 0; i < 4; ++i)
#pragma unroll
        for (int j = 0; j < 2; ++j) acc[i][j] = {0.f,0.f,0.f,0.f};

    int   aaS[2][2][4];
    float wtS[2][2][4];
    float4 offv;

    auto load_off = [&](int kpos){
        const float* op = offb + (size_t)(2*kpos)*4096;
        offv.x = op[p0]; offv.y = op[4096 + p0];
        offv.z = op[p1]; offv.w = op[4096 + p1];
    };
    auto state = [&](int kpos){
        int kh = kpos/3, kw = kpos - kh*3;
        int st = kpos & 1;
        float dy[2] = {offv.x, offv.z}, dx[2] = {offv.y, offv.w};
        int wo[2] = {p0, p1};
#pragma unroll
        for (int jt = 0; jt < 2; ++jt){
            float py = (float)(t + kh - 1) + dy[jt];
            float px = (float)(wo[jt] + kw - 1) + dx[jt];
            float y0f = floorf(py), x0f = floorf(px);
            float ly = py - y0f, lx = px - x0f;
            int y0 = (int)y0f, x0 = (int)x0f;
            int y1 = y0 + 1, x1 = x0 + 1;
            float my0 = (y0>=0 && y0<Hh)?1.f:0.f;
            float my1 = (y1>=0 && y1<Hh)?1.f:0.f;
            float mx0 = (x0>=0 && x0<Ww)?1.f:0.f;
            float mx1 = (x1>=0 && x1<Ww)?1.f:0.f;
            float oy = 1.f - ly, ox = 1.f - lx;
            wtS[st][jt][0] = oy*ox*my0*mx0;
            wtS[st][jt][1] = oy*lx*my0*mx1;
            wtS[st][jt][2] = ly*ox*my1*mx0;
            wtS[st][jt][3] = ly*lx*my1*mx1;
            int cy0 = min(max(y0,0),Hh-1), cy1 = min(max(y1,0),Hh-1);
            int cx0 = min(max(x0,0),Ww-1), cx1 = min(max(x1,0),Ww-1);
            aaS[st][jt][0] = (cy0*Ww + cx0)*CIN;
            aaS[st][jt][1] = (cy0*Ww + cx1)*CIN;
            aaS[st][jt][2] = (cy1*Ww + cx0)*CIN;
            aaS[st][jt][3] = (cy1*Ww + cx1)*CIN;
        }
    };
    auto gather = [&](int c, uint4 q[8]){
        int st = (c >> 2) & 1;
        const u16* xc = xb + ((c & 3) << 5) + quad*8;
#pragma unroll
        for (int jt = 0; jt < 2; ++jt)
#pragma unroll
            for (int cc = 0; cc < 4; ++cc)
                q[jt*4+cc] = *(const uint4*)(xc + aaS[st][jt][cc]);
    };
    auto loadA = [&](int c, uint4 a[4]){
        const u16* wp = Wt + (size_t)((c*8 + wm*4)*64 + lane)*8;
#pragma unroll
        for (int i = 0; i < 4; ++i)
            a[i] = *(const uint4*)(wp + (size_t)i*64*8);
    };
    auto blend = [&](const uint4 q[8], int st, bf16x8 bf[2]){
#pragma unroll
        for (int jt = 0; jt < 2; ++jt){
            u32 r4[4];
#pragma unroll
            for (int d = 0; d < 4; ++d){
                f32x2 s = {0.f, 0.f};
#pragma unroll
                for (int c = 0; c < 4; ++c){
                    u32 u = ((const u32*)q)[(jt*4+c)*4 + d];
                    f32x2 v = { bflo(u), bfhi(u) };
                    f32x2 w2 = { wtS[st][jt][c], wtS[st][jt][c] };
                    s += w2 * v;               // v_pk_fma_f32 candidate
                }
                r4[d] = pack2(s.x, s.y);
            }
            bf[jt] = *(bf16x8*)&r4[0];
        }
    };

    // --- prologue ---
    uint4 q[2][8], av[2][4];
    bf16x8 bf[2];
    load_off(0);
    state(0);
    load_off(1);
    gather(0, q[0]); loadA(0, av[0]);
    gather(1, q[1]);
    blend(q[0], 0, bf);

#pragma unroll 4
    for (int ks = 0; ks < NKSTEP; ++ks){
        int c1 = ks + 1, c2 = ks + 2;
        if (c2 < NKSTEP){
            if ((c2 & 3) == 0){
                int kp = c2 >> 2;
                state(kp);
                if (kp < 8) load_off(kp + 1);
            }
            gather(c2, q[c2 & 1]);             // 2 chunks in flight, vmcnt never 0
        }
        if (c1 < NKSTEP) loadA(c1, av[c1 & 1]);

#pragma unroll
        for (int i = 0; i < 4; ++i){
            bf16x8 a = *(bf16x8*)&av[ks & 1][i];
#pragma unroll
            for (int j = 0; j < 2; ++j)
                acc[i][j] = __builtin_amdgcn_mfma_f32_16x16x32_bf16(a, bf[j], acc[i][j], 0, 0, 0);
        }
        if (c1 < NKSTEP) blend(q[c1 & 1], (c1 >> 2) & 1, bf);
    }

    // epilogue: D[row=quad*4+r][col=l16] + bias
#pragma unroll
    for (int i = 0; i < 4; ++i){
        int cout0 = (wm*4 + i)*16 + quad*4;
#pragma unroll
        for (int j = 0; j < 2; ++j){
            int pcol = (wn*2 + j)*16 + l16;
            size_t obase = ((size_t)(b*COUT + cout0))*4096 + (s0 + pcol);
#pragma unroll
            for (int r = 0; r < 4; ++r)
                out[obase + (size_t)r*4096] = acc[i][j][r] + bias[cout0 + r];
        }
    }
}

// ---- launch -----------------------------------------------------------
extern "C" void kernel_launch(void* const* d_in, const int* in_sizes, int n_in,
                              void* d_out, int out_size, void* d_ws, size_t ws_size,
                              hipStream_t stream){
    const float* x    = (const float*)d_in[0];
    const float* off  = (const float*)d_in[1];
    const float* w    = (const float*)d_in[2];
    const float* bias = (const float*)d_in[3];
    float* out = (float*)d_out;

    u16* xT = (u16*)d_ws;            // 8 MB
    u16* Wt = xT + XT_ELEMS;         // 288 KB

    k_transpose<<<dim3(512), dim3(256), 0, stream>>>(x, xT);
    k_wprep    <<<dim3(576), dim3(256), 0, stream>>>(w, Wt);
    k_main     <<<dim3(512), dim3(256), 0, stream>>>(off, bias, xT, Wt, out);
}

// Round 4
// 119.701 us; speedup vs baseline: 1.2695x; 1.2695x over previous
//
#include <hip/hip_runtime.h>

typedef unsigned int   u32;
typedef unsigned short u16;
typedef short bf16x8 __attribute__((ext_vector_type(8)));
typedef float f32x4  __attribute__((ext_vector_type(4)));
typedef float f32x2  __attribute__((ext_vector_type(2)));

#define CIN   128
#define COUT  128
#define Hh    64
#define Ww    64
#define Bb    8
#define NKSTEP 36          // KDIM/32
#define XT_ELEMS (Bb*Hh*Ww*CIN)   // 4,194,304 ushorts (8 MB)

// ---- helpers ----------------------------------------------------------
__device__ __forceinline__ float bflo(u32 u){ return __uint_as_float(u << 16); }
__device__ __forceinline__ float bfhi(u32 u){ return __uint_as_float(u & 0xffff0000u); }

// fast f32x2 -> packed bf16 pair: round-half-up (+0x8000) then byte-perm.
__device__ __forceinline__ u32 pack2(float a, float b){
    u32 lo = __float_as_uint(a) + 0x8000u;
    u32 hi = __float_as_uint(b) + 0x8000u;
    return __builtin_amdgcn_perm(hi, lo, 0x07060302u);
}
__device__ __forceinline__ u16 tobf(float a){
    u32 ua = __float_as_uint(a);
    ua += 0x7fffu + ((ua >> 16) & 1u);
    return (u16)(ua >> 16);
}

// ---- kernel 1: x [B,CIN,H,W] f32 -> xT [B,H,W,CIN] bf16 ---------------
__global__ __launch_bounds__(256) void k_transpose(const float* __restrict__ x,
                                                   u16* __restrict__ xT){
    __shared__ float lds[64*132];
    int bi = blockIdx.x;
    int hb = bi & 63, b = bi >> 6;
    int tid = threadIdx.x;

    {   // phase 1: read 128 cin-rows x 64 hw, write transposed to LDS
        int r = tid >> 1, cq = tid & 1;
        const float* xp = x + ((size_t)(b*128 + r))*4096 + hb*64 + cq*32;
        float4 v[8];
#pragma unroll
        for (int k = 0; k < 8; ++k) v[k] = *(const float4*)(xp + k*4);
        float* dst = lds + (cq*32)*132 + r;
#pragma unroll
        for (int k = 0; k < 8; ++k){
            dst[(k*4+0)*132] = v[k].x;
            dst[(k*4+1)*132] = v[k].y;
            dst[(k*4+2)*132] = v[k].z;
            dst[(k*4+3)*132] = v[k].w;
        }
    }
    __syncthreads();
    {   // phase 2: per hw row, pack 32 cin -> 16 dwords, full-line stores
        int s = tid >> 2, kq = tid & 3;
        const float* src = lds + s*132 + kq*32;
        u32 r16[16];
#pragma unroll
        for (int k = 0; k < 8; ++k){
            float4 v = *(const float4*)(src + k*4);
            r16[k*2  ] = pack2(v.x, v.y);
            r16[k*2+1] = pack2(v.z, v.w);
        }
        u32* dst = (u32*)xT + ((size_t)(b*4096 + hb*64 + s))*64 + kq*16;
#pragma unroll
        for (int k = 0; k < 4; ++k)
            *(uint4*)(dst + k*4) = *(uint4*)&r16[k*4];
    }
}

// ---- kernel 2: weight [COUT,CIN,3,3] f32 -> Wt bf16, A-fragment order --
__global__ __launch_bounds__(256) void k_wprep(const float* __restrict__ w,
                                               u16* __restrict__ Wt){
    int gid = blockIdx.x*256 + threadIdx.x;     // 0 .. 147455
    int jf   = gid & 7;
    int lane = (gid >> 3) & 63;
    int mt   = (gid >> 9) & 7;
    int kt   = gid >> 12;
    int m  = mt*16 + (lane & 15);
    int kk = (lane >> 4)*8 + jf;
    int ck = kt*32 + kk;
    int kpos = ck >> 7;
    int cin  = ck & 127;
    Wt[gid] = tobf(w[((size_t)m*128 + cin)*9 + kpos]);
}

// ---- kernel 3: fused deform-im2col + MFMA GEMM, 4 blocks/CU -----------
// grid 1024: b = bi&7 (XCD-local batch), t = bi>>3 -> 32-pos tile.
// C-tile 128(cout) x 32(pos); 4 waves: wm -> 64-cout half, wn -> 16-pos half.
// Producer: 8 threads/pos x 4 cin, uint2 corner gathers, pk_fma blend,
// LDS double-buffer, ONE __syncthreads per K-iter.
__global__ __launch_bounds__(256, 4)
void k_main(const float* __restrict__ off, const float* __restrict__ bias,
            const u16* __restrict__ xT, const u16* __restrict__ Wt,
            float* __restrict__ out){
    // V chunk: 32 rows(pos) x 32 bf16(k); row stride 20 dwords (80B)
    __shared__ u32 Vsm[2][32*20];

    int tid = threadIdx.x;
    int bi  = blockIdx.x;
    int b   = bi & 7;
    int t   = bi >> 3;          // 0..127
    int s0  = t * 32;
    int ho  = s0 >> 6, wo0 = s0 & 63;

    // producer identity: 8 threads per position (4 cin each)
    int p = tid >> 3, o = tid & 7;
    int wo = wo0 + p;
    const u16* xb = xT + (size_t)b * (Hh*Ww*CIN);

    // consumer identity
    int lane = tid & 63, wave = tid >> 6;
    int wm = wave >> 1, wn = wave & 1;
    int quad = lane >> 4, l16 = lane & 15;

    f32x4 acc[4];
#pragma unroll
    for (int i = 0; i < 4; ++i) acc[i] = {0.f, 0.f, 0.f, 0.f};

    int   aa[4];
    float wt[4];

    auto state = [&](int kpos){
        int kh = kpos / 3, kw = kpos - kh*3;
        size_t ob = ((size_t)(b*18 + 2*kpos))*4096 + (s0 + p);
        float dy = off[ob];
        float dx = off[ob + 4096];
        float py = (float)(ho + kh - 1) + dy;
        float px = (float)(wo + kw - 1) + dx;
        float y0f = floorf(py), x0f = floorf(px);
        float ly = py - y0f, lx = px - x0f;
        int y0 = (int)y0f, x0 = (int)x0f;
        int y1 = y0 + 1,  x1 = x0 + 1;
        float my0 = (y0 >= 0 && y0 < Hh) ? 1.f : 0.f;
        float my1 = (y1 >= 0 && y1 < Hh) ? 1.f : 0.f;
        float mx0 = (x0 >= 0 && x0 < Ww) ? 1.f : 0.f;
        float mx1 = (x1 >= 0 && x1 < Ww) ? 1.f : 0.f;
        float oy = 1.f - ly, ox = 1.f - lx;
        wt[0] = oy*ox*my0*mx0;
        wt[1] = oy*lx*my0*mx1;
        wt[2] = ly*ox*my1*mx0;
        wt[3] = ly*lx*my1*mx1;
        int cy0 = min(max(y0,0),Hh-1), cy1 = min(max(y1,0),Hh-1);
        int cx0 = min(max(x0,0),Ww-1), cx1 = min(max(x1,0),Ww-1);
        aa[0] = (cy0*Ww + cx0)*CIN;
        aa[1] = (cy0*Ww + cx1)*CIN;
        aa[2] = (cy1*Ww + cx0)*CIN;
        aa[3] = (cy1*Ww + cx1)*CIN;
    };

    auto gather = [&](int ks, uint2 q[4]){
        int coff = ((ks & 3) << 5) + o*4;
        const u16* xc = xb + coff;
#pragma unroll
        for (int c = 0; c < 4; ++c)
            q[c] = *(const uint2*)(xc + aa[c]);
    };

    auto loadA = [&](int ks, uint4 a[4]){
        const u16* wp = Wt + (size_t)((ks*8 + wm*4)*64 + lane)*8;
#pragma unroll
        for (int i = 0; i < 4; ++i)
            a[i] = *(const uint4*)(wp + (size_t)i*64*8);
    };

    auto blend_store = [&](const uint2 q[4], int buf){
        u32 r2[2];
#pragma unroll
        for (int d = 0; d < 2; ++d){
            f32x2 s = {0.f, 0.f};
#pragma unroll
            for (int c = 0; c < 4; ++c){
                u32 u = ((const u32*)q)[c*2 + d];
                f32x2 v  = { bflo(u), bfhi(u) };
                f32x2 w2 = { wt[c], wt[c] };
                s += w2 * v;                    // v_pk_fma_f32
            }
            r2[d] = pack2(s.x, s.y);
        }
        *(uint2*)&Vsm[buf][p*20 + o*2] = *(uint2*)&r2[0];
    };

    // --- prologue: chunk 0 ---
    uint2 q[4];
    uint4 araw_cur[4], araw_nxt[4];
    state(0);
    gather(0, q);
    loadA(0, araw_cur);
    blend_store(q, 0);

    for (int ks = 0; ks < NKSTEP; ++ks){
        __syncthreads();               // V chunk ks visible in buf ks&1
        int nxt = ks + 1;
        bool have_nxt = (nxt < NKSTEP);
        if (have_nxt){
            if ((nxt & 3) == 0) state(nxt >> 2);
            gather(nxt, q);            // loads in flight across MFMAs
            loadA(nxt, araw_nxt);
        }

        // consume chunk ks from Vsm[ks&1]
        uint4 braw = *(const uint4*)&Vsm[ks & 1][(wn*16 + l16)*20 + quad*4];
        bf16x8 bv = __builtin_bit_cast(bf16x8, braw);
#pragma unroll
        for (int i = 0; i < 4; ++i){
            bf16x8 av = __builtin_bit_cast(bf16x8, araw_cur[i]);
            acc[i] = __builtin_amdgcn_mfma_f32_16x16x32_bf16(av, bv, acc[i], 0, 0, 0);
        }

        if (have_nxt){
            blend_store(q, nxt & 1);
#pragma unroll
            for (int i = 0; i < 4; ++i) araw_cur[i] = araw_nxt[i];
        }
    }

    // epilogue: D[row=quad*4+r][col=l16] + bias
    int pcol = wn*16 + l16;
#pragma unroll
    for (int i = 0; i < 4; ++i){
        int cout0 = (wm*4 + i)*16 + quad*4;
        size_t obase = ((size_t)(b*COUT + cout0))*4096 + (s0 + pcol);
#pragma unroll
        for (int r = 0; r < 4; ++r)
            out[obase + (size_t)r*4096] = acc[i][r] + bias[cout0 + r];
    }
}

// ---- launch -----------------------------------------------------------
extern "C" void kernel_launch(void* const* d_in, const int* in_sizes, int n_in,
                              void* d_out, int out_size, void* d_ws, size_t ws_size,
                              hipStream_t stream){
    const float* x    = (const float*)d_in[0];
    const float* off  = (const float*)d_in[1];
    const float* w    = (const float*)d_in[2];
    const float* bias = (const float*)d_in[3];
    float* out = (float*)d_out;

    u16* xT = (u16*)d_ws;            // 8 MB
    u16* Wt = xT + XT_ELEMS;         // 288 KB

    k_transpose<<<dim3(512),  dim3(256), 0, stream>>>(x, xT);
    k_wprep    <<<dim3(576),  dim3(256), 0, stream>>>(w, Wt);
    k_main     <<<dim3(1024), dim3(256), 0, stream>>>(off, bias, xT, Wt, out);
}

// Round 5
// 118.341 us; speedup vs baseline: 1.2841x; 1.0115x over previous
//
#include <hip/hip_runtime.h>

typedef unsigned int   u32;
typedef unsigned short u16;
typedef short bf16x8 __attribute__((ext_vector_type(8)));
typedef float f32x4  __attribute__((ext_vector_type(4)));
typedef float f32x2  __attribute__((ext_vector_type(2)));

#define CIN   128
#define COUT  128
#define Hh    64
#define Ww    64
#define Bb    8
#define NKSTEP 36          // KDIM/32
#define XT_ELEMS (Bb*Hh*Ww*CIN)   // 4,194,304 ushorts (8 MB)

// ---- helpers ----------------------------------------------------------
__device__ __forceinline__ float bflo(u32 u){ return __uint_as_float(u << 16); }
__device__ __forceinline__ float bfhi(u32 u){ return __uint_as_float(u & 0xffff0000u); }

// fast f32x2 -> packed bf16 pair: round-half-up (+0x8000) then byte-perm.
__device__ __forceinline__ u32 pack2(float a, float b){
    u32 lo = __float_as_uint(a) + 0x8000u;
    u32 hi = __float_as_uint(b) + 0x8000u;
    return __builtin_amdgcn_perm(hi, lo, 0x07060302u);
}
__device__ __forceinline__ u16 tobf(float a){
    u32 ua = __float_as_uint(a);
    ua += 0x7fffu + ((ua >> 16) & 1u);
    return (u16)(ua >> 16);
}

// ---- kernel 1: x [B,CIN,H,W] f32 -> xT [B,H,W,CIN] bf16 ---------------
__global__ __launch_bounds__(256) void k_transpose(const float* __restrict__ x,
                                                   u16* __restrict__ xT){
    __shared__ float lds[64*132];
    int bi = blockIdx.x;
    int hb = bi & 63, b = bi >> 6;
    int tid = threadIdx.x;

    {   // phase 1: read 128 cin-rows x 64 hw, write transposed to LDS
        int r = tid >> 1, cq = tid & 1;
        const float* xp = x + ((size_t)(b*128 + r))*4096 + hb*64 + cq*32;
        float4 v[8];
#pragma unroll
        for (int k = 0; k < 8; ++k) v[k] = *(const float4*)(xp + k*4);
        float* dst = lds + (cq*32)*132 + r;
#pragma unroll
        for (int k = 0; k < 8; ++k){
            dst[(k*4+0)*132] = v[k].x;
            dst[(k*4+1)*132] = v[k].y;
            dst[(k*4+2)*132] = v[k].z;
            dst[(k*4+3)*132] = v[k].w;
        }
    }
    __syncthreads();
    {   // phase 2: per hw row, pack 32 cin -> 16 dwords, full-line stores
        int s = tid >> 2, kq = tid & 3;
        const float* src = lds + s*132 + kq*32;
        u32 r16[16];
#pragma unroll
        for (int k = 0; k < 8; ++k){
            float4 v = *(const float4*)(src + k*4);
            r16[k*2  ] = pack2(v.x, v.y);
            r16[k*2+1] = pack2(v.z, v.w);
        }
        u32* dst = (u32*)xT + ((size_t)(b*4096 + hb*64 + s))*64 + kq*16;
#pragma unroll
        for (int k = 0; k < 4; ++k)
            *(uint4*)(dst + k*4) = *(uint4*)&r16[k*4];
    }
}

// ---- kernel 2: weight [COUT,CIN,3,3] f32 -> Wt bf16, A-fragment order --
__global__ __launch_bounds__(256) void k_wprep(const float* __restrict__ w,
                                               u16* __restrict__ Wt){
    int gid = blockIdx.x*256 + threadIdx.x;     // 0 .. 147455
    int jf   = gid & 7;
    int lane = (gid >> 3) & 63;
    int mt   = (gid >> 9) & 7;
    int kt   = gid >> 12;
    int m  = mt*16 + (lane & 15);
    int kk = (lane >> 4)*8 + jf;
    int ck = kt*32 + kk;
    int kpos = ck >> 7;
    int cin  = ck & 127;
    Wt[gid] = tobf(w[((size_t)m*128 + cin)*9 + kpos]);
}

// ---- kernel 3: fused deform-im2col + MFMA GEMM, depth-2 pipeline ------
// grid 1024: b = bi&7 (XCD-local batch), t = bi>>3 -> 32-pos tile.
// C-tile 128(cout) x 32(pos). Pipeline per iter ks (fully unrolled):
//   barrier -> gather chunk ks+2 (reg ring) + loadA ks+1 -> ds_read/MFMA ks
//   -> blend+LDS-store chunk ks+1.  Gather->blend distance ~1.5 iters.
__global__ __launch_bounds__(256, 4)
void k_main(const float* __restrict__ off, const float* __restrict__ bias,
            const u16* __restrict__ xT, const u16* __restrict__ Wt,
            float* __restrict__ out){
    __shared__ u32 Vsm[2][32*20];   // 32 pos x 32 bf16, row stride 20 dw

    int tid = threadIdx.x;
    int bi  = blockIdx.x;
    int b   = bi & 7;
    int t   = bi >> 3;
    int s0  = t * 32;
    int ho  = s0 >> 6, wo0 = s0 & 63;

    int p = tid >> 3, o = tid & 7;      // producer: 8 thr/pos x 4 cin
    int wo = wo0 + p;
    const u16* xb = xT + (size_t)b * (Hh*Ww*CIN);
    const float* offp = off + ((size_t)b*18)*4096 + s0 + p;

    int lane = tid & 63, wave = tid >> 6;
    int wm = wave >> 1, wn = wave & 1;
    int quad = lane >> 4, l16 = lane & 15;

    f32x4 acc[4];
#pragma unroll
    for (int i = 0; i < 4; ++i) acc[i] = {0.f, 0.f, 0.f, 0.f};

    int   aaS[2][4];
    float wtS[2][4];
    float dyN, dxN;                      // prefetched offsets (next kpos)

    auto load_off = [&](int kpos){
        const float* op = offp + (size_t)(2*kpos)*4096;
        dyN = op[0];
        dxN = op[4096];
    };
    auto state = [&](int kpos, int st){  // st = kpos&1 (compile-time at call)
        float dy = dyN, dx = dxN;
        if (kpos < 8) load_off(kpos + 1);   // 4 iters of lead for next kpos
        int kh = kpos / 3, kw = kpos - kh*3;
        float py = (float)(ho + kh - 1) + dy;
        float px = (float)(wo + kw - 1) + dx;
        float y0f = floorf(py), x0f = floorf(px);
        float ly = py - y0f, lx = px - x0f;
        int y0 = (int)y0f, x0 = (int)x0f;
        int y1 = y0 + 1,  x1 = x0 + 1;
        float my0 = (y0 >= 0 && y0 < Hh) ? 1.f : 0.f;
        float my1 = (y1 >= 0 && y1 < Hh) ? 1.f : 0.f;
        float mx0 = (x0 >= 0 && x0 < Ww) ? 1.f : 0.f;
        float mx1 = (x1 >= 0 && x1 < Ww) ? 1.f : 0.f;
        float oy = 1.f - ly, ox = 1.f - lx;
        wtS[st][0] = oy*ox*my0*mx0;
        wtS[st][1] = oy*lx*my0*mx1;
        wtS[st][2] = ly*ox*my1*mx0;
        wtS[st][3] = ly*lx*my1*mx1;
        int cy0 = min(max(y0,0),Hh-1), cy1 = min(max(y1,0),Hh-1);
        int cx0 = min(max(x0,0),Ww-1), cx1 = min(max(x1,0),Ww-1);
        aaS[st][0] = (cy0*Ww + cx0)*CIN;
        aaS[st][1] = (cy0*Ww + cx1)*CIN;
        aaS[st][2] = (cy1*Ww + cx0)*CIN;
        aaS[st][3] = (cy1*Ww + cx1)*CIN;
    };
    auto gather = [&](int c, uint2 q[4]){
        int st = (c >> 2) & 1;
        const u16* xc = xb + ((c & 3) << 5) + o*4;
#pragma unroll
        for (int cc = 0; cc < 4; ++cc)
            q[cc] = *(const uint2*)(xc + aaS[st][cc]);
    };
    auto loadA = [&](int c, uint4 a[4]){
        const u16* wp = Wt + (size_t)((c*8 + wm*4)*64 + lane)*8;
#pragma unroll
        for (int i = 0; i < 4; ++i)
            a[i] = *(const uint4*)(wp + (size_t)i*64*8);
    };
    auto blend_store = [&](const uint2 q[4], int st, int buf){
        u32 r2[2];
#pragma unroll
        for (int d = 0; d < 2; ++d){
            f32x2 s = {0.f, 0.f};
#pragma unroll
            for (int c = 0; c < 4; ++c){
                u32 u = ((const u32*)q)[c*2 + d];
                f32x2 v  = { bflo(u), bfhi(u) };
                f32x2 w2 = { wtS[st][c], wtS[st][c] };
                s += w2 * v;                    // v_pk_fma_f32
            }
            r2[d] = pack2(s.x, s.y);
        }
        *(uint2*)&Vsm[buf][p*20 + o*2] = *(uint2*)&r2[0];
    };

    // --- prologue: chunks 0,1 gathered; chunk 0 blended into Vsm[0] ---
    uint2 qb[2][4];
    uint4 av[2][4];
    load_off(0);
    state(0, 0);                 // consumes kpos0 offsets, prefetches kpos1
    gather(0, qb[0]);
    loadA(0, av[0]);
    blend_store(qb[0], 0, 0);
    gather(1, qb[1]);

#pragma unroll
    for (int ks = 0; ks < NKSTEP; ++ks){
        __syncthreads();                 // Vsm[ks&1] holds chunk ks
        int c1 = ks + 1, c2 = ks + 2;
        if (c2 < NKSTEP){
            if ((c2 & 3) == 0) state(c2 >> 2, (c2 >> 2) & 1);
            gather(c2, qb[ks & 1]);      // chunk ks already blended last iter
        }
        if (c1 < NKSTEP) loadA(c1, av[c1 & 1]);

        uint4 braw = *(const uint4*)&Vsm[ks & 1][(wn*16 + l16)*20 + quad*4];
        bf16x8 bv = __builtin_bit_cast(bf16x8, braw);
#pragma unroll
        for (int i = 0; i < 4; ++i){
            bf16x8 avv = __builtin_bit_cast(bf16x8, av[ks & 1][i]);
            acc[i] = __builtin_amdgcn_mfma_f32_16x16x32_bf16(avv, bv, acc[i], 0, 0, 0);
        }

        if (c1 < NKSTEP)
            blend_store(qb[c1 & 1], (c1 >> 2) & 1, c1 & 1);
    }

    // epilogue: D[row=quad*4+r][col=l16] + bias
    int pcol = wn*16 + l16;
#pragma unroll
    for (int i = 0; i < 4; ++i){
        int cout0 = (wm*4 + i)*16 + quad*4;
        size_t obase = ((size_t)(b*COUT + cout0))*4096 + (s0 + pcol);
#pragma unroll
        for (int r = 0; r < 4; ++r)
            out[obase + (size_t)r*4096] = acc[i][r] + bias[cout0 + r];
    }
}

// ---- launch -----------------------------------------------------------
extern "C" void kernel_launch(void* const* d_in, const int* in_sizes, int n_in,
                              void* d_out, int out_size, void* d_ws, size_t ws_size,
                              hipStream_t stream){
    const float* x    = (const float*)d_in[0];
    const float* off  = (const float*)d_in[1];
    const float* w    = (const float*)d_in[2];
    const float* bias = (const float*)d_in[3];
    float* out = (float*)d_out;

    u16* xT = (u16*)d_ws;            // 8 MB
    u16* Wt = xT + XT_ELEMS;         // 288 KB

    k_transpose<<<dim3(512),  dim3(256), 0, stream>>>(x, xT);
    k_wprep    <<<dim3(576),  dim3(256), 0, stream>>>(w, Wt);
    k_main     <<<dim3(1024), dim3(256), 0, stream>>>(off, bias, xT, Wt, out);
}

// Round 6
// 113.006 us; speedup vs baseline: 1.3447x; 1.0472x over previous
//
#include <hip/hip_runtime.h>

typedef unsigned int   u32;
typedef unsigned short u16;
typedef short bf16x8 __attribute__((ext_vector_type(8)));
typedef float f32x4  __attribute__((ext_vector_type(4)));
typedef float f32x2  __attribute__((ext_vector_type(2)));

#define CIN   128
#define COUT  128
#define Hh    64
#define Ww    64
#define Bb    8
#define NKPOS 9
#define XT_ELEMS (Bb*Hh*Ww*CIN)   // 4,194,304 ushorts (8 MB)

// ---- helpers ----------------------------------------------------------
__device__ __forceinline__ float bflo(u32 u){ return __uint_as_float(u << 16); }
__device__ __forceinline__ float bfhi(u32 u){ return __uint_as_float(u & 0xffff0000u); }

// fast f32x2 -> packed bf16 pair: round-half-up (+0x8000) then byte-perm.
__device__ __forceinline__ u32 pack2(float a, float b){
    u32 lo = __float_as_uint(a) + 0x8000u;
    u32 hi = __float_as_uint(b) + 0x8000u;
    return __builtin_amdgcn_perm(hi, lo, 0x07060302u);
}
__device__ __forceinline__ u16 tobf(float a){
    u32 ua = __float_as_uint(a);
    ua += 0x7fffu + ((ua >> 16) & 1u);
    return (u16)(ua >> 16);
}

// ---- kernel 1: x [B,CIN,H,W] f32 -> xT [B,H,W,CIN] bf16 ---------------
__global__ __launch_bounds__(256) void k_transpose(const float* __restrict__ x,
                                                   u16* __restrict__ xT){
    __shared__ float lds[64*132];
    int bi = blockIdx.x;
    int hb = bi & 63, b = bi >> 6;
    int tid = threadIdx.x;

    {   // phase 1: read 128 cin-rows x 64 hw, write transposed to LDS
        int r = tid >> 1, cq = tid & 1;
        const float* xp = x + ((size_t)(b*128 + r))*4096 + hb*64 + cq*32;
        float4 v[8];
#pragma unroll
        for (int k = 0; k < 8; ++k) v[k] = *(const float4*)(xp + k*4);
        float* dst = lds + (cq*32)*132 + r;
#pragma unroll
        for (int k = 0; k < 8; ++k){
            dst[(k*4+0)*132] = v[k].x;
            dst[(k*4+1)*132] = v[k].y;
            dst[(k*4+2)*132] = v[k].z;
            dst[(k*4+3)*132] = v[k].w;
        }
    }
    __syncthreads();
    {   // phase 2: per hw row, pack 32 cin -> 16 dwords, full-line stores
        int s = tid >> 2, kq = tid & 3;
        const float* src = lds + s*132 + kq*32;
        u32 r16[16];
#pragma unroll
        for (int k = 0; k < 8; ++k){
            float4 v = *(const float4*)(src + k*4);
            r16[k*2  ] = pack2(v.x, v.y);
            r16[k*2+1] = pack2(v.z, v.w);
        }
        u32* dst = (u32*)xT + ((size_t)(b*4096 + hb*64 + s))*64 + kq*16;
#pragma unroll
        for (int k = 0; k < 4; ++k)
            *(uint4*)(dst + k*4) = *(uint4*)&r16[k*4];
    }
}

// ---- kernel 2: weight [COUT,CIN,3,3] f32 -> Wt bf16, A-fragment order --
__global__ __launch_bounds__(256) void k_wprep(const float* __restrict__ w,
                                               u16* __restrict__ Wt){
    int gid = blockIdx.x*256 + threadIdx.x;     // 0 .. 147455
    int jf   = gid & 7;
    int lane = (gid >> 3) & 63;
    int mt   = (gid >> 9) & 7;
    int kt   = gid >> 12;
    int m  = mt*16 + (lane & 15);
    int kk = (lane >> 4)*8 + jf;
    int ck = kt*32 + kk;
    int kpos = ck >> 7;
    int cin  = ck & 127;
    Wt[gid] = tobf(w[((size_t)m*128 + cin)*9 + kpos]);
}

// ---- kernel 3: fused deform-im2col + MFMA GEMM, BK=128 intervals ------
// grid 512: b = bi&7 (XCD-local batch), t = bi>>3 = ho row; 128cout x 64pos.
// 9 barrier intervals (one kernel-position each): per wave-interval
// 32 MFMA + 8 ds_read_b128. Gathers for kpos g+1 issued right after the
// barrier, blended at interval end -> the MFMA body covers their latency
// INSIDE one barrier interval (vmcnt(0) drain at s_barrier no longer bites).
__global__ __launch_bounds__(256, 2)
void k_main(const float* __restrict__ off, const float* __restrict__ bias,
            const u16* __restrict__ xT, const u16* __restrict__ Wt,
            float* __restrict__ out){
    // V: [2 buf][4 chunk][64 pos][20 dw]  (chunk = 32 cin slice)
    __shared__ u32 Vsm[2][4*64*20];        // 40 KB

    int tid = threadIdx.x, bi = blockIdx.x;
    int b = bi & 7, t = bi >> 3;           // t = ho row
    int s0 = t * 64;

    int p = tid >> 2, qt = tid & 3;        // 4 thr/pos, 32 cin each
    const u16* xb = xT + (size_t)b * (Hh*Ww*CIN);
    const float* offp = off + ((size_t)b*18)*4096 + s0 + p;

    int lane = tid & 63, wave = tid >> 6;
    int wm = wave >> 1, wn = wave & 1;
    int quad = lane >> 4, l16 = lane & 15;

    f32x4 acc[4][2];
#pragma unroll
    for (int i = 0; i < 4; ++i)
#pragma unroll
        for (int j = 0; j < 2; ++j) acc[i][j] = {0.f,0.f,0.f,0.f};

    int   aaS[2][4];
    float wtS[2][4];
    float dyN, dxN;
    uint4 ring[4][4];                      // [corner][32-cin subblock]
    uint4 av[2][4];

    auto load_off = [&](int kpos){
        const float* op = offp + (size_t)(2*kpos)*4096;
        dyN = op[0];
        dxN = op[4096];
    };
    auto state = [&](int kpos, int st){
        float dy = dyN, dx = dxN;
        int kh = kpos / 3, kw = kpos - kh*3;
        float py = (float)(t + kh - 1) + dy;
        float px = (float)(p + kw - 1) + dx;
        float y0f = floorf(py), x0f = floorf(px);
        float ly = py - y0f, lx = px - x0f;
        int y0 = (int)y0f, x0 = (int)x0f;
        int y1 = y0 + 1,  x1 = x0 + 1;
        float my0 = (y0 >= 0 && y0 < Hh) ? 1.f : 0.f;
        float my1 = (y1 >= 0 && y1 < Hh) ? 1.f : 0.f;
        float mx0 = (x0 >= 0 && x0 < Ww) ? 1.f : 0.f;
        float mx1 = (x1 >= 0 && x1 < Ww) ? 1.f : 0.f;
        float oy = 1.f - ly, ox = 1.f - lx;
        wtS[st][0] = oy*ox*my0*mx0;
        wtS[st][1] = oy*lx*my0*mx1;
        wtS[st][2] = ly*ox*my1*mx0;
        wtS[st][3] = ly*lx*my1*mx1;
        int cy0 = min(max(y0,0),Hh-1), cy1 = min(max(y1,0),Hh-1);
        int cx0 = min(max(x0,0),Ww-1), cx1 = min(max(x1,0),Ww-1);
        aaS[st][0] = (cy0*Ww + cx0)*CIN;
        aaS[st][1] = (cy0*Ww + cx1)*CIN;
        aaS[st][2] = (cy1*Ww + cx0)*CIN;
        aaS[st][3] = (cy1*Ww + cx1)*CIN;
    };
    auto gather = [&](int st){             // full 128-cin per corner, coalesced
#pragma unroll
        for (int c = 0; c < 4; ++c){
            const u16* xc = xb + aaS[st][c] + qt*32;
#pragma unroll
            for (int s = 0; s < 4; ++s)
                ring[c][s] = *(const uint4*)(xc + s*8);
        }
    };
    auto loadA = [&](int gc, uint4 a[4]){
        const u16* wp = Wt + (size_t)((gc*8 + wm*4)*64 + lane)*8;
#pragma unroll
        for (int i = 0; i < 4; ++i)
            a[i] = *(const uint4*)(wp + (size_t)i*64*8);
    };
    auto blend_store = [&](int st, int buf){
        u32* dst = &Vsm[buf][qt*1280 + p*20];
#pragma unroll
        for (int s = 0; s < 4; ++s){
            u32 r4[4];
#pragma unroll
            for (int d = 0; d < 4; ++d){
                f32x2 s2 = {0.f, 0.f};
#pragma unroll
                for (int c = 0; c < 4; ++c){
                    u32 u = ((const u32*)&ring[c][s])[d];
                    f32x2 v  = { bflo(u), bfhi(u) };
                    f32x2 w2 = { wtS[st][c], wtS[st][c] };
                    s2 += w2 * v;          // v_pk_fma_f32
                }
                r4[d] = pack2(s2.x, s2.y);
            }
            *(uint2*)(dst + s*4    ) = *(uint2*)&r4[0];
            *(uint2*)(dst + s*4 + 2) = *(uint2*)&r4[2];
        }
    };

    // --- prologue: kpos0 gathered+blended into buf0; kpos1 state ready ---
    load_off(0);
    state(0, 0);
    gather(0);
    load_off(1);
    state(1, 1);
    blend_store(0, 0);
    loadA(0, av[0]);

#pragma unroll
    for (int g = 0; g < NKPOS; ++g){
        __syncthreads();                   // buf[g&1] holds kpos g
        if (g + 1 < NKPOS) gather((g + 1) & 1);     // state from prev interval
        if (g + 2 < NKPOS) load_off(g + 2);

#pragma unroll
        for (int c = 0; c < 4; ++c){
            int gc = g*4 + c;
            if (gc + 1 < 4*NKPOS) loadA(gc + 1, av[(gc + 1) & 1]);

            uint4 braw[2];
#pragma unroll
            for (int j = 0; j < 2; ++j)
                braw[j] = *(const uint4*)&Vsm[g & 1][c*1280 + ((wn*2 + j)*16 + l16)*20 + quad*4];
#pragma unroll
            for (int i = 0; i < 4; ++i){
                bf16x8 avv = __builtin_bit_cast(bf16x8, av[gc & 1][i]);
#pragma unroll
                for (int j = 0; j < 2; ++j){
                    bf16x8 bv = __builtin_bit_cast(bf16x8, braw[j]);
                    acc[i][j] = __builtin_amdgcn_mfma_f32_16x16x32_bf16(avv, bv, acc[i][j], 0, 0, 0);
                }
            }
        }

        if (g + 2 < NKPOS) state(g + 2, g & 1);     // slot (g+2)&1 == g&1
        if (g + 1 < NKPOS) blend_store((g + 1) & 1, (g + 1) & 1);
    }

    // epilogue: D[row=quad*4+r][col=l16] + bias
#pragma unroll
    for (int i = 0; i < 4; ++i){
        int cout0 = (wm*4 + i)*16 + quad*4;
#pragma unroll
        for (int j = 0; j < 2; ++j){
            int pcol = (wn*2 + j)*16 + l16;
            size_t obase = ((size_t)(b*COUT + cout0))*4096 + (s0 + pcol);
#pragma unroll
            for (int r = 0; r < 4; ++r)
                out[obase + (size_t)r*4096] = acc[i][j][r] + bias[cout0 + r];
        }
    }
}

// ---- launch -----------------------------------------------------------
extern "C" void kernel_launch(void* const* d_in, const int* in_sizes, int n_in,
                              void* d_out, int out_size, void* d_ws, size_t ws_size,
                              hipStream_t stream){
    const float* x    = (const float*)d_in[0];
    const float* off  = (const float*)d_in[1];
    const float* w    = (const float*)d_in[2];
    const float* bias = (const float*)d_in[3];
    float* out = (float*)d_out;

    u16* xT = (u16*)d_ws;            // 8 MB
    u16* Wt = xT + XT_ELEMS;         // 288 KB

    k_transpose<<<dim3(512), dim3(256), 0, stream>>>(x, xT);
    k_wprep    <<<dim3(576), dim3(256), 0, stream>>>(w, Wt);
    k_main     <<<dim3(512), dim3(256), 0, stream>>>(off, bias, xT, Wt, out);
}